// Round 1
// baseline (385.095 us; speedup 1.0000x reference)
//
#include <hip/hip_runtime.h>
#include <math.h>

// SteerableKernel: rotate [O,I,9,9] fp32 weights by G=8 angles via bilinear
// grid_sample (zeros padding, align_corners=False).
// Output layout: out[g][o][i][y][x] = sample(in[o][i], grid_g)[y][x]
//   flat: (g*C + c)*81 + p  with c = o*I+i, p = y*9+x.
//
// Phase 1: tiny kernel builds a 648-entry table in d_ws:
//   per (g,p): 4 bilinear weights (validity folded in) + 4 source BYTE offsets.
// Phase 2: channel-sweep kernel. Thread owns a fixed p (table entry in
//   registers per g), lanes cover channels; input staged in LDS; stores are
//   block-consecutive dwords (coalesced).

#define KS   9
#define NPIX 81
#define NC   128    // channels per block (LDS tile = 128*81*4 = 41472 B)
#define BLOCK 256

__global__ void st_make_table(float* __restrict__ tab, int G) {
    int i = blockIdx.x * blockDim.x + threadIdx.x;
    if (i >= G * NPIX) return;
    int g = i / NPIX;
    int p = i - g * NPIX;
    int py = p / KS, px = p - py * KS;
    double theta = 6.283185307179586 * (double)g / (double)G;
    double cth = cos(theta), sth = sin(theta);
    double lx = ((double)px + 0.5) * (2.0 / KS) - 1.0;   // x = lin[px] (width)
    double ly = ((double)py + 0.5) * (2.0 / KS) - 1.0;   // y = lin[py] (height)
    double gx = cth * lx - sth * ly;
    double gy = sth * lx + cth * ly;
    double ix = ((gx + 1.0) * KS - 1.0) * 0.5;           // unnormalize, W=9
    double iy = ((gy + 1.0) * KS - 1.0) * 0.5;           // H=9
    double ix0 = floor(ix), iy0 = floor(iy);
    double fx = ix - ix0, fy = iy - iy0;
    int xi0 = (int)ix0, yi0 = (int)iy0;
    float w[4]; int o[4];
#pragma unroll
    for (int k = 0; k < 4; ++k) {
        int dx = k & 1, dy = k >> 1;
        int xi = xi0 + dx, yi = yi0 + dy;
        bool valid = (xi >= 0) && (xi < KS) && (yi >= 0) && (yi < KS);
        double wv = (dy ? fy : 1.0 - fy) * (dx ? fx : 1.0 - fx);
        int xc = xi < 0 ? 0 : (xi > KS - 1 ? KS - 1 : xi);
        int yc = yi < 0 ? 0 : (yi > KS - 1 ? KS - 1 : yi);
        w[k] = valid ? (float)wv : 0.0f;
        o[k] = (yc * KS + xc) * 4;   // byte offset within a channel's 81 floats
    }
    float4* e0 = (float4*)(tab + (size_t)i * 8);
    *e0 = make_float4(w[0], w[1], w[2], w[3]);
    int4* e1 = (int4*)(tab + (size_t)i * 8 + 4);
    *e1 = make_int4(o[0], o[1], o[2], o[3]);
}

__global__ __launch_bounds__(BLOCK) void st_rotate(
        const float* __restrict__ in, const float* __restrict__ tab,
        float* __restrict__ out, int C, int G) {
    __shared__ __align__(16) float lin[NC * NPIX];
    const int t = threadIdx.x;
    const int c0 = blockIdx.x * NC;

    // Stage NC channels into LDS, coalesced float4 (c0*81 is 4-dword aligned).
    {
        const float4* src = (const float4*)(in + (size_t)c0 * NPIX);
        float4* dst = (float4*)lin;
        for (int j = t; j < NC * NPIX / 4; j += BLOCK) dst[j] = src[j];
    }
    __syncthreads();

    if (t < 3 * NPIX) {                 // 243 active threads
        const int c_local = t / NPIX;   // 0..2
        const int p = t - c_local * NPIX;
        const float4* tab4 = (const float4*)tab;
        for (int g = 0; g < G; ++g) {
            const float4 w = tab4[(size_t)(g * NPIX + p) * 2];
            const int4  o = ((const int4*)tab4)[(size_t)(g * NPIX + p) * 2 + 1];
            // store base: out[(g*C + c0 + c)*81 + p] with c = cc + c_local
            //   = base_g + cc*81 + t  -> consecutive dwords across block
            float* og = out + ((size_t)g * C + c0) * NPIX + t;
            const char* lb = (const char*)lin + c_local * (NPIX * 4);
            for (int cc = 0; cc < NC; cc += 3) {
                if (cc + c_local < NC) {
                    float v = *(const float*)(lb + o.x) * w.x
                            + *(const float*)(lb + o.y) * w.y
                            + *(const float*)(lb + o.z) * w.z
                            + *(const float*)(lb + o.w) * w.w;
                    *og = v;
                }
                lb += 3 * NPIX * 4;
                og += 3 * NPIX;
            }
        }
    }
}

extern "C" void kernel_launch(void* const* d_in, const int* in_sizes, int n_in,
                              void* d_out, int out_size, void* d_ws, size_t ws_size,
                              hipStream_t stream) {
    const float* in = (const float*)d_in[0];
    float* out = (float*)d_out;
    float* tab = (float*)d_ws;                 // 648 * 32 B = 20736 B scratch
    const int C = in_sizes[0] / NPIX;          // 131072 channels (O*I)
    const int G = out_size / in_sizes[0];      // 8 rotations
    const int ents = G * NPIX;
    st_make_table<<<(ents + 255) / 256, 256, 0, stream>>>(tab, G);
    st_rotate<<<C / NC, BLOCK, 0, stream>>>(in, tab, out, C, G);
}